// Round 4
// baseline (257.048 us; speedup 1.0000x reference)
//
#include <hip/hip_runtime.h>

#define V  25
#define NE 5
#define NT 300
#define NC 12
#define CI 3
#define CO 64
#define NK 15   // NE*CI
#define TT 6    // t-tile per block
#define NTHREADS 256

__global__ __launch_bounds__(NTHREADS) void hyper_graphconv_kernel(
    const float* __restrict__ x,
    const float* __restrict__ h0, const float* __restrict__ h1,
    const float* __restrict__ h2, const float* __restrict__ h3,
    const float* __restrict__ h4,
    const float* __restrict__ wmlp, const float* __restrict__ bmlp,
    float* __restrict__ out)
{
    __shared__ float  h_lds[NE][V][V];        // h is exactly 0/1
    __shared__ double de[NE][V];
    __shared__ float  wm[CO * NK];
    __shared__ float  bm[CO];
    __shared__ double wE[NE][TT][V];          // exact fp32 values; later g = de*w
    __shared__ double feat[CI][TT][V];
    __shared__ double dv[NE][TT][V];
    __shared__ double fproj[NE][CI][TT][V];
    __shared__ double sup[NE][CI][TT][V];

    const int tid = threadIdx.x;
    const int b  = blockIdx.y;
    const int t0 = blockIdx.x * TT;

    // ---- stage 0: load h matrices, mlp weights ----
    {
        const float* hp;
        #pragma unroll
        for (int i = 0; i < NE; ++i) {
            switch (i) {
                case 0: hp = h0; break;
                case 1: hp = h1; break;
                case 2: hp = h2; break;
                case 3: hp = h3; break;
                default: hp = h4; break;
            }
            for (int idx = tid; idx < V * V; idx += NTHREADS)
                h_lds[i][idx / V][idx % V] = hp[idx];
        }
    }
    for (int idx = tid; idx < CO * NK; idx += NTHREADS) wm[idx] = wmlp[idx];
    if (tid < CO) bm[tid] = bmlp[tid];

    // ---- stage 0b: load x channels ----
    // edge-weight channels {6,7,9,10,11}: ch = i + 6 + (i>=2)
    for (int idx = tid; idx < NE * TT * V; idx += NTHREADS) {
        int i = idx / (TT * V);
        int r = idx % (TT * V);
        int t = r / V, v = r % V;
        int ch = i + 6 + (i >= 2 ? 1 : 0);
        wE[i][t][v] = (double)x[((size_t)(b * NC + ch) * NT + (t0 + t)) * V + v];
    }
    for (int idx = tid; idx < CI * TT * V; idx += NTHREADS) {
        int c = idx / (TT * V);
        int r = idx % (TT * V);
        int t = r / V, v = r % V;
        feat[c][t][v] = (double)x[((size_t)(b * NC + c) * NT + (t0 + t)) * V + v];
    }
    __syncthreads();

    // ---- stage 1: de[i][e] = 1/sum_v h[i][v][e] (0 if 0) ----
    if (tid < NE * V) {
        int i = tid / V, e = tid % V;
        double s = 0.0;
        #pragma unroll
        for (int v = 0; v < V; ++v) s += (double)h_lds[i][v][e];
        de[i][e] = (s != 0.0) ? (1.0 / s) : 0.0;
    }
    // dv: REPRODUCE NUMPY'S FP32 SUMMATION for degree_v = sum_e h[v,e]*w[t,e].
    // numpy c_einsum contig-dot (baseline SSE, no FMA): 4 lane partials with
    // e = j, j+4, ..., j+20 accumulated sequentially (mul and add separately
    // rounded), horizontal ((L0+L1)+(L2+L3)), then scalar tail e=24.
    // Products h*w are exact (h in {0,1}) so only this association matters.
    // R1-R3 established: ref's degree_v is fp32; exact fp64 misses by 2.08%.
    for (int idx = tid; idx < NE * TT * V; idx += NTHREADS) {
        int i = idx / (TT * V);
        int r = idx % (TT * V);
        int t = r / V, v = r % V;
        const float* hv = &h_lds[i][v][0];
        float L0 = 0.f, L1 = 0.f, L2 = 0.f, L3 = 0.f;
        #pragma unroll
        for (int k = 0; k < 6; ++k) {
            int e = 4 * k;
            L0 = __fadd_rn(L0, __fmul_rn(hv[e + 0], (float)wE[i][t][e + 0]));
            L1 = __fadd_rn(L1, __fmul_rn(hv[e + 1], (float)wE[i][t][e + 1]));
            L2 = __fadd_rn(L2, __fmul_rn(hv[e + 2], (float)wE[i][t][e + 2]));
            L3 = __fadd_rn(L3, __fmul_rn(hv[e + 3], (float)wE[i][t][e + 3]));
        }
        float s = __fadd_rn(__fadd_rn(L0, L1), __fadd_rn(L2, L3));
        s = __fadd_rn(s, __fmul_rn(hv[24], (float)wE[i][t][24]));
        dv[i][t][v] = (s > 0.f) ? (1.0 / sqrt((double)s)) : 0.0;
    }
    __syncthreads();

    // ---- stage 2: fold de into w (g = de*w, in place); fproj ----
    for (int idx = tid; idx < NE * TT * V; idx += NTHREADS) {
        int i = idx / (TT * V);
        int r = idx % (TT * V);
        int t = r / V, e = r % V;
        wE[i][t][e] *= de[i][e];
    }
    __syncthreads();
    // fproj[i][c][t][e] = sum_u h[i][u][e] * dv[i][t][u] * feat[c][t][u]
    for (int idx = tid; idx < NE * CI * TT * V; idx += NTHREADS) {
        int i  = idx / (CI * TT * V);
        int r  = idx % (CI * TT * V);
        int c  = r / (TT * V);
        int r2 = r % (TT * V);
        int t = r2 / V, e = r2 % V;
        double s = 0.0;
        #pragma unroll
        for (int u = 0; u < V; ++u)
            s += (double)h_lds[i][u][e] * (dv[i][t][u] * feat[c][t][u]);
        fproj[i][c][t][e] = s;
    }
    __syncthreads();

    // ---- stage 3: sup[i][c][t][v] = dv[i][t][v] * sum_e h[i][v][e]*g[i][t][e]*fproj[i][c][t][e] ----
    for (int idx = tid; idx < NE * CI * TT * V; idx += NTHREADS) {
        int i  = idx / (CI * TT * V);
        int r  = idx % (CI * TT * V);
        int c  = r / (TT * V);
        int r2 = r % (TT * V);
        int t = r2 / V, v = r2 % V;
        double s = 0.0;
        #pragma unroll
        for (int e = 0; e < V; ++e)
            s += (double)h_lds[i][v][e] * (wE[i][t][e] * fproj[i][c][t][e]);
        sup[i][c][t][v] = dv[i][t][v] * s;
    }
    __syncthreads();

    // ---- stage 4: MLP epilogue + relu ----
    for (int idx = tid; idx < CO * TT * V; idx += NTHREADS) {
        int o = idx / (TT * V);
        int r = idx % (TT * V);
        int t = r / V, v = r % V;
        double s = (double)bm[o];
        #pragma unroll
        for (int k = 0; k < NK; ++k)
            s += (double)wm[o * NK + k] * sup[k / 3][k % 3][t][v];
        out[((size_t)(b * CO + o) * NT + (t0 + t)) * V + v] = fmaxf((float)s, 0.f);
    }
}

extern "C" void kernel_launch(void* const* d_in, const int* in_sizes, int n_in,
                              void* d_out, int out_size, void* d_ws, size_t ws_size,
                              hipStream_t stream) {
    const float* x    = (const float*)d_in[0];
    const float* h0   = (const float*)d_in[1];
    const float* h1   = (const float*)d_in[2];
    const float* h2   = (const float*)d_in[3];
    const float* h3   = (const float*)d_in[4];
    const float* h4   = (const float*)d_in[5];
    const float* wmlp = (const float*)d_in[6];
    const float* bmlp = (const float*)d_in[7];
    float* out = (float*)d_out;

    dim3 grid(NT / TT, 64, 1);   // 50 t-tiles x 64 batches
    dim3 block(NTHREADS, 1, 1);
    hyper_graphconv_kernel<<<grid, block, 0, stream>>>(
        x, h0, h1, h2, h3, h4, wmlp, bmlp, out);
}

// Round 5
// 212.490 us; speedup vs baseline: 1.2097x; 1.2097x over previous
//
#include <hip/hip_runtime.h>

#define V   25
#define VP  28          // padded leading dim (16B-aligned rows: 112B)
#define NE  5
#define NT  300
#define NC  12
#define CI  3
#define CO  64
#define NK  15          // NE*CI
#define TT  6           // t-tile per block
#define NTH 256
#define PP  152         // padded p-range per tile (TT*V=150 -> 152)

typedef float f4 __attribute__((ext_vector_type(4)));

__global__ __launch_bounds__(NTH) void hyper_kernel(
    const float* __restrict__ x,
    const float* __restrict__ h0, const float* __restrict__ h1,
    const float* __restrict__ h2, const float* __restrict__ h3,
    const float* __restrict__ h4,
    const float* __restrict__ wmlp, const float* __restrict__ bmlp,
    float* __restrict__ out)
{
    // all fp32; zero-padded to VP in both dims so 4-wide chunks never read garbage
    __shared__ __align__(16) float hS [NE][VP][VP];   // [i][row v/u][col e]
    __shared__ __align__(16) float hT [NE][VP][VP];   // [i][e][v]
    __shared__ __align__(16) float deS[NE][VP];
    __shared__ __align__(16) float wmT[NK][CO];       // transposed mlp weights
    __shared__ __align__(16) float bmS[CO];
    __shared__ __align__(16) float wraw[NE][TT][VP];  // raw edge-weight channels
    __shared__ __align__(16) float gS  [NE][TT][VP];  // de*w
    __shared__ __align__(16) float featS[CI][TT][VP];
    __shared__ __align__(16) float dvS [NE][TT][VP];
    __shared__ __align__(16) float BS  [NE][CI][TT][VP]; // dv*feat
    __shared__ __align__(16) float fpS [NE][CI][TT][VP]; // g * (h^T B)
    __shared__ __align__(16) float supS[NK][PP];         // [k][p], p = t*V+v

    const int tid = threadIdx.x;
    const int b   = blockIdx.y;
    const int t0b = blockIdx.x * TT;

    // ---------------- S0: staging ----------------
    for (int idx = tid; idx < NE * VP * VP; idx += NTH) {
        int i = idx / (VP * VP), r = idx % (VP * VP), row = r / VP, col = r % VP;
        const float* hp = (i == 0) ? h0 : (i == 1) ? h1 : (i == 2) ? h2 : (i == 3) ? h3 : h4;
        float val = (row < V && col < V) ? hp[row * V + col] : 0.f;
        hS[i][row][col] = val;
        hT[i][col][row] = val;
    }
    for (int idx = tid; idx < CO * NK; idx += NTH) {
        int o = idx / NK, k = idx % NK;
        wmT[k][o] = wmlp[idx];
    }
    if (tid < CO) bmS[tid] = bmlp[tid];
    for (int idx = tid; idx < NE * TT * VP; idx += NTH) {
        int i = idx / (TT * VP), r = idx % (TT * VP), t = r / VP, c = r % VP;
        int ch = i + 6 + (i >= 2 ? 1 : 0);   // {6,7,9,10,11}
        wraw[i][t][c] = (c < V) ? x[((size_t)(b * NC + ch) * NT + t0b + t) * V + c] : 0.f;
    }
    for (int idx = tid; idx < CI * TT * VP; idx += NTH) {
        int cc = idx / (TT * VP), r = idx % (TT * VP), t = r / VP, c = r % VP;
        featS[cc][t][c] = (c < V) ? x[((size_t)(b * NC + cc) * NT + t0b + t) * V + c] : 0.f;
    }
    __syncthreads();

    // ---------------- S1: de, dv ----------------
    for (int idx = tid; idx < NE * VP; idx += NTH) {
        int i = idx / VP, e = idx % VP;
        float s = 0.f;
        #pragma unroll
        for (int v = 0; v < V; ++v) s += hS[i][v][e];
        deS[i][e] = (s != 0.f) ? __fdiv_rn(1.f, s) : 0.f;   // e>=25: s==0 -> 0
    }
    // dv: EXACT numpy-fp32 association (validated in R4). float4 loads are
    // bit-transparent; arithmetic sequence is identical to the passing kernel.
    #define HV(q) (hr[(q) >> 2][(q) & 3])
    #define WV(q) (wr[(q) >> 2][(q) & 3])
    for (int idx = tid; idx < NE * TT * VP; idx += NTH) {
        int i = idx / (TT * VP), r = idx % (TT * VP), t = r / VP, v = r % VP;
        if (v < V) {
            f4 hr[7], wr[7];
            #pragma unroll
            for (int q = 0; q < 7; ++q) {
                hr[q] = *(const f4*)&hS[i][v][4 * q];
                wr[q] = *(const f4*)&wraw[i][t][4 * q];
            }
            float L0 = 0.f, L1 = 0.f, L2 = 0.f, L3 = 0.f;
            #pragma unroll
            for (int k2 = 0; k2 < 6; ++k2) {
                int e = 4 * k2;
                L0 = __fadd_rn(L0, __fmul_rn(HV(e + 0), WV(e + 0)));
                L1 = __fadd_rn(L1, __fmul_rn(HV(e + 1), WV(e + 1)));
                L2 = __fadd_rn(L2, __fmul_rn(HV(e + 2), WV(e + 2)));
                L3 = __fadd_rn(L3, __fmul_rn(HV(e + 3), WV(e + 3)));
            }
            float s = __fadd_rn(__fadd_rn(L0, L1), __fadd_rn(L2, L3));
            s = __fadd_rn(s, __fmul_rn(HV(24), WV(24)));
            dvS[i][t][v] = (s > 0.f) ? (float)(1.0 / sqrt((double)s)) : 0.f;
        } else {
            dvS[i][t][v] = 0.f;
        }
    }
    __syncthreads();

    // ---------------- S2: B = dv*feat ; g = de*w ----------------
    for (int idx = tid; idx < NE * CI * TT * VP; idx += NTH) {
        int i = idx / (CI * TT * VP), r = idx % (CI * TT * VP);
        int c = r / (TT * VP), r2 = r % (TT * VP), t = r2 / VP, u = r2 % VP;
        BS[i][c][t][u] = dvS[i][t][u] * featS[c][t][u];   // pads: 0*0
    }
    for (int idx = tid; idx < NE * TT * VP; idx += NTH) {
        int i = idx / (TT * VP), r = idx % (TT * VP), t = r / VP, e = r % VP;
        gS[i][t][e] = wraw[i][t][e] * deS[i][e];          // pads: 0*0
    }
    __syncthreads();

    // ---------------- S3: fproj[i][c][t][e] = g * sum_u h[u][e]*B[c][u] ----------------
    // register tile: 2t x 3c x 4e, 105 active threads; LDS via b128 only
    if (tid < NE * 3 * 7) {
        int i = tid / 21, r = tid % 21, tg = r / 7, eg = r % 7;
        int e0 = 4 * eg, ta = 2 * tg;
        f4 acc[2][CI];
        #pragma unroll
        for (int tj = 0; tj < 2; ++tj)
            #pragma unroll
            for (int c = 0; c < CI; ++c) acc[tj][c] = (f4){0.f, 0.f, 0.f, 0.f};
        #pragma unroll
        for (int u0 = 0; u0 < VP; u0 += 4) {
            f4 hrow[4];
            #pragma unroll
            for (int ju = 0; ju < 4; ++ju) hrow[ju] = *(const f4*)&hS[i][u0 + ju][e0];
            #pragma unroll
            for (int tj = 0; tj < 2; ++tj)
                #pragma unroll
                for (int c = 0; c < CI; ++c) {
                    f4 bb = *(const f4*)&BS[i][c][ta + tj][u0];
                    acc[tj][c] += hrow[0] * bb.x + hrow[1] * bb.y + hrow[2] * bb.z + hrow[3] * bb.w;
                }
        }
        #pragma unroll
        for (int tj = 0; tj < 2; ++tj)
            #pragma unroll
            for (int c = 0; c < CI; ++c) {
                f4 gg = *(const f4*)&gS[i][ta + tj][e0];
                *(f4*)&fpS[i][c][ta + tj][e0] = acc[tj][c] * gg;  // e-pads: 0*0
            }
    }
    __syncthreads();

    // ---------------- S4: sup[k][p] = dv[v] * sum_e h[v][e]*fp[c][e] ----------------
    if (tid < NE * 3 * 7) {
        int i = tid / 21, r = tid % 21, tg = r / 7, vg = r % 7;
        int v0 = 4 * vg, ta = 2 * tg;
        f4 acc[2][CI];
        #pragma unroll
        for (int tj = 0; tj < 2; ++tj)
            #pragma unroll
            for (int c = 0; c < CI; ++c) acc[tj][c] = (f4){0.f, 0.f, 0.f, 0.f};
        #pragma unroll
        for (int e0 = 0; e0 < VP; e0 += 4) {
            f4 hc[4];
            #pragma unroll
            for (int je = 0; je < 4; ++je) hc[je] = *(const f4*)&hT[i][e0 + je][v0];
            #pragma unroll
            for (int tj = 0; tj < 2; ++tj)
                #pragma unroll
                for (int c = 0; c < CI; ++c) {
                    f4 pp = *(const f4*)&fpS[i][c][ta + tj][e0];
                    acc[tj][c] += hc[0] * pp.x + hc[1] * pp.y + hc[2] * pp.z + hc[3] * pp.w;
                }
        }
        #pragma unroll
        for (int tj = 0; tj < 2; ++tj)
            #pragma unroll
            for (int c = 0; c < CI; ++c) {
                int k = i * CI + c;
                f4 dvv = *(const f4*)&dvS[i][ta + tj][v0];
                f4 res = acc[tj][c] * dvv;
                int p = (ta + tj) * V + v0;
                #pragma unroll
                for (int jv = 0; jv < 4; ++jv)
                    if (v0 + jv < V) supS[k][p + jv] = res[jv];
            }
    }
    if (tid < NK * 2) supS[tid >> 1][150 + (tid & 1)] = 0.f;  // p-pads
    __syncthreads();

    // ---------------- S5: MLP + bias + relu ----------------
    // tile 4o x 4p; p-major lanes -> coalesced stores, contiguous sup b128
    for (int tile = tid; tile < 16 * 38; tile += NTH) {
        int pg = tile % 38, og = tile / 38;
        int o0 = 4 * og, p0 = 4 * pg;
        f4 a0 = (f4){0,0,0,0}, a1 = a0, a2 = a0, a3 = a0;
        #pragma unroll
        for (int k = 0; k < NK; ++k) {
            f4 sv = *(const f4*)&supS[k][p0];
            f4 wv = *(const f4*)&wmT[k][o0];
            a0 += sv * wv.x; a1 += sv * wv.y; a2 += sv * wv.z; a3 += sv * wv.w;
        }
        #pragma unroll
        for (int io = 0; io < 4; ++io) {
            int o = o0 + io;
            f4 av = (io == 0) ? a0 : (io == 1) ? a1 : (io == 2) ? a2 : a3;
            float bias = bmS[o];
            size_t ob = ((size_t)(b * CO + o) * NT + t0b) * V + p0;
            #pragma unroll
            for (int jp = 0; jp < 4; ++jp)
                if (p0 + jp < TT * V) out[ob + jp] = fmaxf(av[jp] + bias, 0.f);
        }
    }
}

extern "C" void kernel_launch(void* const* d_in, const int* in_sizes, int n_in,
                              void* d_out, int out_size, void* d_ws, size_t ws_size,
                              hipStream_t stream) {
    const float* x    = (const float*)d_in[0];
    const float* h0   = (const float*)d_in[1];
    const float* h1   = (const float*)d_in[2];
    const float* h2   = (const float*)d_in[3];
    const float* h3   = (const float*)d_in[4];
    const float* h4   = (const float*)d_in[5];
    const float* wmlp = (const float*)d_in[6];
    const float* bmlp = (const float*)d_in[7];
    float* out = (float*)d_out;

    dim3 grid(NT / TT, 64, 1);
    dim3 block(NTH, 1, 1);
    hyper_kernel<<<grid, block, 0, stream>>>(x, h0, h1, h2, h3, h4, wmlp, bmlp, out);
}

// Round 7
// 161.483 us; speedup vs baseline: 1.5918x; 1.3159x over previous
//
#include <hip/hip_runtime.h>

#define NE  5
#define V   25
#define NT  300
#define NC  12
#define CO  64
#define TPW 5           // t's per wave
#define WPB 4           // waves per block
#define TPB (TPW*WPB)   // 20 t per block

typedef float f4 __attribute__((ext_vector_type(4)));

// select w if bit e of m set, else +0.0 (bit-AND; also kills garbage bits).
// Sum-equivalent to numpy's h*w products (+0.0 vs ±0.0 never changes a sum
// whose running value can only be +0.0 before the first nonzero term).
__device__ __forceinline__ float hsel(unsigned m, int e, float w) {
    int s = ((int)(m << (31 - e))) >> 31;   // 0 or -1
    return __int_as_float(__float_as_int(w) & s);
}

// per-wave scratch float offsets (rows 28 floats = 112B, all 16B-aligned)
#define OW   0      // W[8][28]   rows 0-4: edge w, rows 5-7: feat
#define ODV  224    // DV[5][28]
#define OG   364    // G[5][28]
#define OB   504    // BB[3][5][28]  (c,i,u)
#define OFP  924    // FP[15][28]    (k,e)  g-folded fproj
#define OST  1344   // ST[25][20]    (v,k)  sup, k=15 zeroed
#define SCRF 1844   // floats per wave (7376B)

__global__ __launch_bounds__(256, 4) void hyper_main(
    const float* __restrict__ x,
    const float* __restrict__ h0, const float* __restrict__ h1,
    const float* __restrict__ h2, const float* __restrict__ h3,
    const float* __restrict__ h4,
    const float* __restrict__ wmlp, const float* __restrict__ bmlp,
    float* __restrict__ out)
{
    __shared__ unsigned RM[125];           // row masks [i*25+v] over e
    __shared__ unsigned CM[125];           // col masks [i*25+e] over u
    __shared__ float    DE[125];           // 1/degree_e
    __shared__ float    WMs[CO*16];        // [o][k], k=15 zero
    __shared__ float    BMs[CO];
    __shared__ __align__(16) float SCR[WPB][SCRF];

    const int tid  = threadIdx.x;
    const int lane = tid & 63;
    const int wid  = tid >> 6;
    const int b    = blockIdx.y;

    // ---- block init (once): masks + de computed IN-KERNEL (no d_ws) ----
    if (tid < 125) {                       // row mask over e for (i, v)
        int i = tid / 25, v = tid % 25;
        const float* hp = (i==0)?h0:(i==1)?h1:(i==2)?h2:(i==3)?h3:h4;
        unsigned m = 0;
        for (int e = 0; e < V; ++e) if (hp[v*V + e] != 0.f) m |= (1u << e);
        RM[tid] = m;
    } else if (tid < 250) {                // col mask over u + de for (i, e)
        int idx = tid - 125, i = idx / 25, e = idx % 25;
        const float* hp = (i==0)?h0:(i==1)?h1:(i==2)?h2:(i==3)?h3:h4;
        unsigned m = 0; float s = 0.f;
        for (int u = 0; u < V; ++u) {
            float hv = hp[u*V + e];
            s += hv;
            if (hv != 0.f) m |= (1u << u);
        }
        CM[idx] = m;
        DE[idx] = (s != 0.f) ? __fdiv_rn(1.f, s) : 0.f;
    }
    for (int q = tid; q < CO*15; q += 256) { int o = q/15, k = q%15; WMs[o*16+k] = wmlp[q]; }
    if (tid < CO) { WMs[tid*16+15] = 0.f; BMs[tid] = bmlp[tid]; }
    __syncthreads();

    float* S = SCR[wid];

    for (int j = 0; j < TPW; ++j) {
        const int t = blockIdx.x * TPB + wid * TPW + j;

        // ---- LOAD: 8 channels x 25 -> W rows (edge w: {6,7,9,10,11}; feat: {0,1,2})
        for (int q = lane; q < 200; q += 64) {
            int ch = q / 25, e = q % 25;
            int xc = (ch < 5) ? (ch + 6 + (ch >= 2 ? 1 : 0)) : (ch - 5);
            S[OW + ch*28 + e] = x[((size_t)(b*NC + xc)*NT + t)*V + e];
        }
        __syncthreads();

        // ---- dv: bit-exact numpy fp32 association (L0..L3 mod-4 + tree + tail)
        for (int r = 0; r < 2; ++r) {
            int idx = r*64 + lane;
            if (idx < 125) {
                int i = idx / 25, v = idx % 25;
                unsigned m = RM[idx];
                const float* wi = S + OW + i*28;
                f4 w0 = *(const f4*)(wi+0),  w1 = *(const f4*)(wi+4),
                   w2 = *(const f4*)(wi+8),  w3 = *(const f4*)(wi+12),
                   w4 = *(const f4*)(wi+16), w5 = *(const f4*)(wi+20),
                   w6 = *(const f4*)(wi+24);
                float L0 = 0.f, L1 = 0.f, L2 = 0.f, L3 = 0.f;
                L0=__fadd_rn(L0,hsel(m, 0,w0.x)); L1=__fadd_rn(L1,hsel(m, 1,w0.y));
                L2=__fadd_rn(L2,hsel(m, 2,w0.z)); L3=__fadd_rn(L3,hsel(m, 3,w0.w));
                L0=__fadd_rn(L0,hsel(m, 4,w1.x)); L1=__fadd_rn(L1,hsel(m, 5,w1.y));
                L2=__fadd_rn(L2,hsel(m, 6,w1.z)); L3=__fadd_rn(L3,hsel(m, 7,w1.w));
                L0=__fadd_rn(L0,hsel(m, 8,w2.x)); L1=__fadd_rn(L1,hsel(m, 9,w2.y));
                L2=__fadd_rn(L2,hsel(m,10,w2.z)); L3=__fadd_rn(L3,hsel(m,11,w2.w));
                L0=__fadd_rn(L0,hsel(m,12,w3.x)); L1=__fadd_rn(L1,hsel(m,13,w3.y));
                L2=__fadd_rn(L2,hsel(m,14,w3.z)); L3=__fadd_rn(L3,hsel(m,15,w3.w));
                L0=__fadd_rn(L0,hsel(m,16,w4.x)); L1=__fadd_rn(L1,hsel(m,17,w4.y));
                L2=__fadd_rn(L2,hsel(m,18,w4.z)); L3=__fadd_rn(L3,hsel(m,19,w4.w));
                L0=__fadd_rn(L0,hsel(m,20,w5.x)); L1=__fadd_rn(L1,hsel(m,21,w5.y));
                L2=__fadd_rn(L2,hsel(m,22,w5.z)); L3=__fadd_rn(L3,hsel(m,23,w5.w));
                float s = __fadd_rn(__fadd_rn(L0,L1), __fadd_rn(L2,L3));
                s = __fadd_rn(s, hsel(m, 24, w6.x));
                S[ODV + i*28 + v] = (s > 0.f) ? (float)(1.0 / sqrt((double)s)) : 0.f;
            }
        }
        __syncthreads();

        // ---- g = w*de ; B = dv*feat  (500 items)
        for (int r = 0; r < 8; ++r) {
            int idx = r*64 + lane;
            if (idx < 125) {
                int i = idx / 25, e = idx % 25;
                S[OG + i*28 + e] = S[OW + i*28 + e] * DE[idx];
            } else if (idx < 500) {
                int q = idx - 125, c = q / 125, rem = q % 125, i = rem / 25, u = rem % 25;
                S[OB + (c*5+i)*28 + u] = S[ODV + i*28 + u] * S[OW + (5+c)*28 + u];
            }
        }
        __syncthreads();

        // ---- fproj (g-folded): FP[k][e] = g[i][e] * sum_u h[u,e]*B[c][i][u]
        for (int r = 0; r < 6; ++r) {
            int idx = r*64 + lane;
            if (idx < 375) {
                int k = idx / 25, e = idx % 25, i = k / 3, c = k % 3;
                unsigned cm = CM[i*25 + e];
                const float* bb = S + OB + (c*5+i)*28;
                float acc = 0.f;
                #pragma unroll
                for (int u0 = 0; u0 < 28; u0 += 4) {
                    f4 bv = *(const f4*)(bb + u0);
                    acc = __fadd_rn(acc, hsel(cm, u0+0, bv.x));
                    acc = __fadd_rn(acc, hsel(cm, u0+1, bv.y));
                    acc = __fadd_rn(acc, hsel(cm, u0+2, bv.z));
                    acc = __fadd_rn(acc, hsel(cm, u0+3, bv.w));
                }
                S[OFP + k*28 + e] = acc * S[OG + i*28 + e];
            }
        }
        __syncthreads();

        // ---- sup: ST[v][k] = dv[v] * sum_e h[v,e]*FP[k][e] ; zero k=15 slot
        for (int r = 0; r < 7; ++r) {
            int idx = r*64 + lane;
            if (idx < 375) {
                int k = idx / 25, v = idx % 25, i = k / 3;
                unsigned rm = RM[i*25 + v];
                const float* fp = S + OFP + k*28;
                float acc = 0.f;
                #pragma unroll
                for (int e0 = 0; e0 < 28; e0 += 4) {
                    f4 fv = *(const f4*)(fp + e0);
                    acc = __fadd_rn(acc, hsel(rm, e0+0, fv.x));
                    acc = __fadd_rn(acc, hsel(rm, e0+1, fv.y));
                    acc = __fadd_rn(acc, hsel(rm, e0+2, fv.z));
                    acc = __fadd_rn(acc, hsel(rm, e0+3, fv.w));
                }
                S[OST + v*20 + k] = S[ODV + i*28 + v] * acc;
            } else if (idx < 400) {
                S[OST + (idx-375)*20 + 15] = 0.f;
            }
        }
        __syncthreads();

        // ---- MLP: lanes (o2 in [0,2), v in [0,25)); ST row cached in regs
        if (lane < 50) {
            int o2 = lane / 25, v = lane % 25;
            const float* st = S + OST + v*20;
            f4 s0 = *(const f4*)(st+0), s1 = *(const f4*)(st+4),
               s2 = *(const f4*)(st+8), s3 = *(const f4*)(st+12);
            #pragma unroll
            for (int oi = 0; oi < 32; ++oi) {
                int o = oi*2 + o2;
                const float* wm = WMs + o*16;
                f4 m0 = *(const f4*)(wm+0), m1 = *(const f4*)(wm+4),
                   m2 = *(const f4*)(wm+8), m3 = *(const f4*)(wm+12);
                float a = BMs[o];
                a = fmaf(m0.x, s0.x, a); a = fmaf(m0.y, s0.y, a);
                a = fmaf(m0.z, s0.z, a); a = fmaf(m0.w, s0.w, a);
                a = fmaf(m1.x, s1.x, a); a = fmaf(m1.y, s1.y, a);
                a = fmaf(m1.z, s1.z, a); a = fmaf(m1.w, s1.w, a);
                a = fmaf(m2.x, s2.x, a); a = fmaf(m2.y, s2.y, a);
                a = fmaf(m2.z, s2.z, a); a = fmaf(m2.w, s2.w, a);
                a = fmaf(m3.x, s3.x, a); a = fmaf(m3.y, s3.y, a);
                a = fmaf(m3.z, s3.z, a); a = fmaf(m3.w, s3.w, a);
                out[((size_t)(b*CO + o)*NT + t)*V + v] = fmaxf(a, 0.f);
            }
        }
        __syncthreads();   // ST/W reuse safety across loop iterations
    }
}

extern "C" void kernel_launch(void* const* d_in, const int* in_sizes, int n_in,
                              void* d_out, int out_size, void* d_ws, size_t ws_size,
                              hipStream_t stream) {
    const float* x    = (const float*)d_in[0];
    const float* h0   = (const float*)d_in[1];
    const float* h1   = (const float*)d_in[2];
    const float* h2   = (const float*)d_in[3];
    const float* h3   = (const float*)d_in[4];
    const float* h4   = (const float*)d_in[5];
    const float* wmlp = (const float*)d_in[6];
    const float* bmlp = (const float*)d_in[7];
    float* out = (float*)d_out;

    hyper_main<<<dim3(NT/TPB, 64, 1), dim3(256,1,1), 0, stream>>>(
        x, h0, h1, h2, h3, h4, wmlp, bmlp, out);
}

// Round 8
// 96.265 us; speedup vs baseline: 2.6702x; 1.6775x over previous
//
#include <hip/hip_runtime.h>

#define NE  5
#define V   25
#define NT  300
#define NC  12
#define CO  64
#define WPB   4       // waves per block
#define NPAIR 3       // t-pairs per wave

typedef float f4 __attribute__((ext_vector_type(4)));

// intra-wave LDS ordering: drain this wave's LDS ops + pin compiler ordering.
#define WSYNC() do { asm volatile("s_waitcnt lgkmcnt(0)" ::: "memory"); \
                     __builtin_amdgcn_sched_barrier(0); } while (0)

// select w if bit e of m set, else +0.0 (sum-equivalent to h*w, h in {0,1})
__device__ __forceinline__ float hsel(unsigned m, int e, float w) {
    int s = ((int)(m << (31 - e))) >> 31;
    return __int_as_float(__float_as_int(w) & s);
}

// per-wave scratch float offsets (rows 28 floats = 112B; OST rows 20 floats)
#define OW   0      // W[8][28]   rows 0-4 edge w, rows 5-7 feat
#define ODV  224    // DV[5][28]
#define OG   364    // G[5][28]
#define OB   504    // B[3][5][28]   (c,i,u)
#define OFP  924    // FP[15][28]    (k=3i+c, e)
#define OST  1344   // ST[50][20]    row = tp*25+v, k cols 0..15 (15 zeroed in regs)
#define SCRF 2344   // floats per wave (9376B, 16B-aligned stride)

__global__ __launch_bounds__(256, 4) void hyper_main(
    const float* __restrict__ x,
    const float* __restrict__ h0, const float* __restrict__ h1,
    const float* __restrict__ h2, const float* __restrict__ h3,
    const float* __restrict__ h4,
    const float* __restrict__ wmlp, const float* __restrict__ bmlp,
    float* __restrict__ out)
{
    __shared__ unsigned RM[125];   // row masks [i*25+v] over e
    __shared__ unsigned CM[125];   // col masks [i*25+e] over u
    __shared__ float    DE[125];   // 1/degree_e
    __shared__ __align__(16) float SCR[WPB][SCRF];

    const int tid  = threadIdx.x;
    const int lane = tid & 63;
    const int wid  = tid >> 6;
    const int b    = blockIdx.y;

    // ---- block init (once). NOTE: all branches covered by 256 threads
    // (R6's fatal bug was a 250..374 branch with only 256 threads). ----
    if (tid < 125) {                       // row mask over e for (i, v)
        int i = tid / 25, v = tid % 25;
        const float* hp = (i==0)?h0:(i==1)?h1:(i==2)?h2:(i==3)?h3:h4;
        unsigned m = 0;
        for (int e = 0; e < V; ++e) if (hp[v*V + e] != 0.f) m |= (1u << e);
        RM[tid] = m;
    } else if (tid < 250) {                // col mask over u + de for (i, e)
        int idx = tid - 125, i = idx / 25, e = idx % 25;
        const float* hp = (i==0)?h0:(i==1)?h1:(i==2)?h2:(i==3)?h3:h4;
        unsigned m = 0; float s = 0.f;
        for (int u = 0; u < V; ++u) {
            float hv = hp[u*V + e];
            s += hv;
            if (hv != 0.f) m |= (1u << u);
        }
        CM[idx] = m;
        DE[idx] = (s != 0.f) ? __fdiv_rn(1.f, s) : 0.f;
    }
    __syncthreads();   // the only block-wide barrier

    float* S = SCR[wid];
    const int wtask = blockIdx.x * WPB + wid;

    for (int j = 0; j < NPAIR; ++j) {
        const int pp = wtask * NPAIR + j;      // t-pair id, t = 2*pp + tp
        if (pp >= NT/2) break;

        for (int tp = 0; tp < 2; ++tp) {
            const int t = pp*2 + tp;

            // ---- P0: load 8 channels x 25 -> W rows ----
            for (int q = lane; q < 200; q += 64) {
                int ch = q / 25, e = q % 25;
                int xc = (ch < 5) ? (ch + 6 + (ch >= 2 ? 1 : 0)) : (ch - 5);
                S[OW + ch*28 + e] = x[((size_t)(b*NC + xc)*NT + t)*V + e];
            }
            WSYNC();

            // ---- P1: dv (bit-exact numpy fp32 association) + g + B fused ----
            for (int r = 0; r < 2; ++r) {
                int idx = r*64 + lane;
                if (idx < 125) {
                    int i = idx / 25, v = idx % 25;
                    unsigned m = RM[idx];
                    const float* wi = S + OW + i*28;
                    f4 w0 = *(const f4*)(wi+0),  w1 = *(const f4*)(wi+4),
                       w2 = *(const f4*)(wi+8),  w3 = *(const f4*)(wi+12),
                       w4 = *(const f4*)(wi+16), w5 = *(const f4*)(wi+20),
                       w6 = *(const f4*)(wi+24);
                    float L0 = 0.f, L1 = 0.f, L2 = 0.f, L3 = 0.f;
                    L0=__fadd_rn(L0,hsel(m, 0,w0.x)); L1=__fadd_rn(L1,hsel(m, 1,w0.y));
                    L2=__fadd_rn(L2,hsel(m, 2,w0.z)); L3=__fadd_rn(L3,hsel(m, 3,w0.w));
                    L0=__fadd_rn(L0,hsel(m, 4,w1.x)); L1=__fadd_rn(L1,hsel(m, 5,w1.y));
                    L2=__fadd_rn(L2,hsel(m, 6,w1.z)); L3=__fadd_rn(L3,hsel(m, 7,w1.w));
                    L0=__fadd_rn(L0,hsel(m, 8,w2.x)); L1=__fadd_rn(L1,hsel(m, 9,w2.y));
                    L2=__fadd_rn(L2,hsel(m,10,w2.z)); L3=__fadd_rn(L3,hsel(m,11,w2.w));
                    L0=__fadd_rn(L0,hsel(m,12,w3.x)); L1=__fadd_rn(L1,hsel(m,13,w3.y));
                    L2=__fadd_rn(L2,hsel(m,14,w3.z)); L3=__fadd_rn(L3,hsel(m,15,w3.w));
                    L0=__fadd_rn(L0,hsel(m,16,w4.x)); L1=__fadd_rn(L1,hsel(m,17,w4.y));
                    L2=__fadd_rn(L2,hsel(m,18,w4.z)); L3=__fadd_rn(L3,hsel(m,19,w4.w));
                    L0=__fadd_rn(L0,hsel(m,20,w5.x)); L1=__fadd_rn(L1,hsel(m,21,w5.y));
                    L2=__fadd_rn(L2,hsel(m,22,w5.z)); L3=__fadd_rn(L3,hsel(m,23,w5.w));
                    float s = __fadd_rn(__fadd_rn(L0,L1), __fadd_rn(L2,L3));
                    s = __fadd_rn(s, hsel(m, 24, w6.x));
                    float dvv = (s > 0.f) ? (float)(1.0 / sqrt((double)s)) : 0.f;
                    S[ODV + i*28 + v] = dvv;
                    S[OG  + i*28 + v] = S[OW + i*28 + v] * DE[idx];
                    float f0 = S[OW + 5*28 + v];
                    float f1 = S[OW + 6*28 + v];
                    float f2 = S[OW + 7*28 + v];
                    S[OB + (0*5+i)*28 + v] = dvv * f0;
                    S[OB + (1*5+i)*28 + v] = dvv * f1;
                    S[OB + (2*5+i)*28 + v] = dvv * f2;
                }
            }
            WSYNC();

            // ---- P2: fproj via column bit-loop: FP[3i+c][e] = g[i][e]*sum_u h[u,e]*B[c][i][u]
            for (int r = 0; r < 2; ++r) {
                int idx = r*64 + lane;
                if (idx < 125) {
                    int i = idx / 25, e = idx % 25;
                    unsigned m = CM[idx];
                    const float* bp = S + OB + i*28;
                    float a0 = 0.f, a1 = 0.f, a2 = 0.f;
                    while (m) {
                        int u = __builtin_ctz(m); m &= m - 1;
                        a0 += bp[u]; a1 += bp[140 + u]; a2 += bp[280 + u];
                    }
                    float gg = S[OG + i*28 + e];
                    S[OFP + (i*3+0)*28 + e] = a0 * gg;
                    S[OFP + (i*3+1)*28 + e] = a1 * gg;
                    S[OFP + (i*3+2)*28 + e] = a2 * gg;
                }
            }
            WSYNC();

            // ---- P3: sup via row bit-loop: ST[tp*25+v][3i+c] = dv*sum_e h[v,e]*FP[3i+c][e]
            for (int r = 0; r < 2; ++r) {
                int idx = r*64 + lane;
                if (idx < 125) {
                    int i = idx / 25, v = idx % 25;
                    unsigned m = RM[idx];
                    const float* fp = S + OFP + i*3*28;
                    float a0 = 0.f, a1 = 0.f, a2 = 0.f;
                    while (m) {
                        int e = __builtin_ctz(m); m &= m - 1;
                        a0 += fp[e]; a1 += fp[28 + e]; a2 += fp[56 + e];
                    }
                    float dd = S[ODV + i*28 + v];
                    float* st = S + OST + (tp*25 + v)*20 + i*3;
                    st[0] = a0 * dd; st[1] = a1 * dd; st[2] = a2 * dd;
                }
            }
            WSYNC();
        }

        // ---- P4: MLP + relu + contiguous nontemporal stores (per pair) ----
        // lane = tp*25+v (50 active); per o one store instr covers 200B contiguous.
        if (lane < 50) {
            const float* st = S + OST + lane*20;
            f4 s0 = *(const f4*)(st+0), s1 = *(const f4*)(st+4),
               s2 = *(const f4*)(st+8), s3 = *(const f4*)(st+12);
            s3.w = 0.f;   // k=15 pad slot (never written)
            // out float index: (b*64+o)*7500 + pp*50 + lane
            float* ob = out + (size_t)b*CO*7500 + (size_t)pp*50 + lane;
            #pragma unroll 4
            for (int o = 0; o < CO; ++o) {
                const float* wm = wmlp + o*15;   // wave-uniform -> scalar loads
                float a = bmlp[o];
                a = fmaf(wm[ 0], s0.x, a); a = fmaf(wm[ 1], s0.y, a);
                a = fmaf(wm[ 2], s0.z, a); a = fmaf(wm[ 3], s0.w, a);
                a = fmaf(wm[ 4], s1.x, a); a = fmaf(wm[ 5], s1.y, a);
                a = fmaf(wm[ 6], s1.z, a); a = fmaf(wm[ 7], s1.w, a);
                a = fmaf(wm[ 8], s2.x, a); a = fmaf(wm[ 9], s2.y, a);
                a = fmaf(wm[10], s2.z, a); a = fmaf(wm[11], s2.w, a);
                a = fmaf(wm[12], s3.x, a); a = fmaf(wm[13], s3.y, a);
                a = fmaf(wm[14], s3.z, a);
                __builtin_nontemporal_store(fmaxf(a, 0.f), ob + (size_t)o*7500);
            }
        }
        WSYNC();   // ST reads drained before next pair overwrites
    }
}

extern "C" void kernel_launch(void* const* d_in, const int* in_sizes, int n_in,
                              void* d_out, int out_size, void* d_ws, size_t ws_size,
                              hipStream_t stream) {
    const float* x    = (const float*)d_in[0];
    const float* h0   = (const float*)d_in[1];
    const float* h1   = (const float*)d_in[2];
    const float* h2   = (const float*)d_in[3];
    const float* h3   = (const float*)d_in[4];
    const float* h4   = (const float*)d_in[5];
    const float* wmlp = (const float*)d_in[6];
    const float* bmlp = (const float*)d_in[7];
    float* out = (float*)d_out;

    // 150 t-pairs, WPB*NPAIR=12 pairs per block -> 13 x-blocks (tail guarded)
    dim3 grid((NT/2 + WPB*NPAIR - 1) / (WPB*NPAIR), 64, 1);
    hyper_main<<<grid, dim3(256,1,1), 0, stream>>>(
        x, h0, h1, h2, h3, h4, wmlp, bmlp, out);
}

// Round 9
// 84.118 us; speedup vs baseline: 3.0558x; 1.1444x over previous
//
#include <hip/hip_runtime.h>

#define NE  5
#define V   25
#define NT  300
#define NC  12
#define CO  64
#define WPB 4
#define GX  13
#define NWT (GX*WPB)    // 52 wave-tasks per batch

typedef float f4 __attribute__((ext_vector_type(4)));
typedef float f2 __attribute__((ext_vector_type(2)));

// intra-wave LDS ordering: drain this wave's LDS ops + pin compiler ordering.
#define WSYNC() do { asm volatile("s_waitcnt lgkmcnt(0)" ::: "memory"); \
                     __builtin_amdgcn_sched_barrier(0); } while (0)

// select w if bit e of m set, else +0.0 (sum-equivalent to h*w, h in {0,1})
__device__ __forceinline__ float hsel(unsigned m, int e, float w) {
    int s = ((int)(m << (31 - e))) >> 31;
    return __int_as_float(__float_as_int(w) & s);
}

// per-wave scratch float offsets (rows 28 floats = 112B; OST rows 20 floats)
#define OW   0      // W[8][28]   rows 0-4 edge w, rows 5-7 feat
#define ODV  224    // DV[5][28]
#define OG   364    // G[5][28]
#define OB   504    // B[3][5][28]   (c,i,u)
#define OFP  924    // FP[15][28]    (k=3i+c, e)
#define OST  1344   // ST[50][20]    row = tp*25+v
#define SCRF 2344   // floats per wave

__global__ __launch_bounds__(256, 4) void hyper_main(
    const float* __restrict__ x,
    const float* __restrict__ h0, const float* __restrict__ h1,
    const float* __restrict__ h2, const float* __restrict__ h3,
    const float* __restrict__ h4,
    const float* __restrict__ wmlp, const float* __restrict__ bmlp,
    float* __restrict__ out)
{
    __shared__ unsigned RM[125];   // row masks [i*25+v] over e
    __shared__ unsigned CM[125];   // col masks [i*25+e] over u
    __shared__ float    DE[125];   // 1/degree_e
    __shared__ __align__(16) float SCR[WPB][SCRF];

    const int tid  = threadIdx.x;
    const int lane = tid & 63;
    const int wid  = tid >> 6;
    const int b    = blockIdx.y;

    // ---- block init (all branches within 256 threads) ----
    if (tid < 125) {
        int i = tid / 25, v = tid % 25;
        const float* hp = (i==0)?h0:(i==1)?h1:(i==2)?h2:(i==3)?h3:h4;
        unsigned m = 0;
        for (int e = 0; e < V; ++e) if (hp[v*V + e] != 0.f) m |= (1u << e);
        RM[tid] = m;
    } else if (tid < 250) {
        int idx = tid - 125, i = idx / 25, e = idx % 25;
        const float* hp = (i==0)?h0:(i==1)?h1:(i==2)?h2:(i==3)?h3:h4;
        unsigned m = 0; float s = 0.f;
        for (int u = 0; u < V; ++u) {
            float hv = hp[u*V + e];
            s += hv;
            if (hv != 0.f) m |= (1u << u);
        }
        CM[idx] = m;
        DE[idx] = (s != 0.f) ? __fdiv_rn(1.f, s) : 0.f;
    }
    __syncthreads();   // only block-wide barrier

    float* S = SCR[wid];
    const int wtask = blockIdx.x * WPB + wid;

    // ---- prefetch lane constants: item q = r*64+lane over 200 = 8ch x 25e ----
    const float* xb[4]; int lo[4];
    {
        #pragma unroll
        for (int r = 0; r < 4; ++r) {
            int q  = r*64 + lane;
            int qq = (q < 200) ? q : 0;
            int ch = qq / 25, e = qq % 25;
            int xc = (ch < 5) ? (ch + 6 + (ch >= 2 ? 1 : 0)) : (ch - 5);
            lo[r] = OW + ch*28 + e;
            xb[r] = x + (size_t)(b*NC + xc)*NT*V + e;
        }
    }
    const bool act3 = (lane < 8);      // r=3 valid items: q=192..199

    float pf0 = 0.f, pf1 = 0.f, pf2 = 0.f, pf3 = 0.f;
    if (wtask < 150) {                 // prologue prefetch: t = 2*wtask
        int t0 = 2 * wtask;
        pf0 = xb[0][t0*V]; pf1 = xb[1][t0*V];
        pf2 = xb[2][t0*V]; pf3 = xb[3][t0*V];
    }

    for (int pp = wtask; pp < NT/2; pp += NWT) {
        for (int tp = 0; tp < 2; ++tp) {

            // ---- commit prefetched W (prev t's W-reads drained by prior WSYNC) ----
            S[lo[0]] = pf0; S[lo[1]] = pf1; S[lo[2]] = pf2;
            if (act3) S[lo[3]] = pf3;
            WSYNC();

            // ---- issue next prefetch (hidden under P1-P3/P4 compute) ----
            {
                int tn = (tp == 0) ? (2*pp + 1) : (2*(pp + NWT));
                if (tn < NT) {
                    pf0 = xb[0][tn*V]; pf1 = xb[1][tn*V];
                    pf2 = xb[2][tn*V]; pf3 = xb[3][tn*V];
                }
            }

            // ---- P1: dv (bit-exact numpy fp32 association) + g + B fused ----
            for (int r = 0; r < 2; ++r) {
                int idx = r*64 + lane;
                if (idx < 125) {
                    int i = idx / 25, v = idx % 25;
                    unsigned m = RM[idx];
                    const float* wi = S + OW + i*28;
                    f4 w0 = *(const f4*)(wi+0),  w1 = *(const f4*)(wi+4),
                       w2 = *(const f4*)(wi+8),  w3 = *(const f4*)(wi+12),
                       w4 = *(const f4*)(wi+16), w5 = *(const f4*)(wi+20),
                       w6 = *(const f4*)(wi+24);
                    float L0 = 0.f, L1 = 0.f, L2 = 0.f, L3 = 0.f;
                    L0=__fadd_rn(L0,hsel(m, 0,w0.x)); L1=__fadd_rn(L1,hsel(m, 1,w0.y));
                    L2=__fadd_rn(L2,hsel(m, 2,w0.z)); L3=__fadd_rn(L3,hsel(m, 3,w0.w));
                    L0=__fadd_rn(L0,hsel(m, 4,w1.x)); L1=__fadd_rn(L1,hsel(m, 5,w1.y));
                    L2=__fadd_rn(L2,hsel(m, 6,w1.z)); L3=__fadd_rn(L3,hsel(m, 7,w1.w));
                    L0=__fadd_rn(L0,hsel(m, 8,w2.x)); L1=__fadd_rn(L1,hsel(m, 9,w2.y));
                    L2=__fadd_rn(L2,hsel(m,10,w2.z)); L3=__fadd_rn(L3,hsel(m,11,w2.w));
                    L0=__fadd_rn(L0,hsel(m,12,w3.x)); L1=__fadd_rn(L1,hsel(m,13,w3.y));
                    L2=__fadd_rn(L2,hsel(m,14,w3.z)); L3=__fadd_rn(L3,hsel(m,15,w3.w));
                    L0=__fadd_rn(L0,hsel(m,16,w4.x)); L1=__fadd_rn(L1,hsel(m,17,w4.y));
                    L2=__fadd_rn(L2,hsel(m,18,w4.z)); L3=__fadd_rn(L3,hsel(m,19,w4.w));
                    L0=__fadd_rn(L0,hsel(m,20,w5.x)); L1=__fadd_rn(L1,hsel(m,21,w5.y));
                    L2=__fadd_rn(L2,hsel(m,22,w5.z)); L3=__fadd_rn(L3,hsel(m,23,w5.w));
                    float s = __fadd_rn(__fadd_rn(L0,L1), __fadd_rn(L2,L3));
                    s = __fadd_rn(s, hsel(m, 24, w6.x));
                    float dvv = (s > 0.f) ? (float)(1.0 / sqrt((double)s)) : 0.f;
                    S[ODV + i*28 + v] = dvv;
                    S[OG  + i*28 + v] = S[OW + i*28 + v] * DE[idx];
                    float f0 = S[OW + 5*28 + v];
                    float f1 = S[OW + 6*28 + v];
                    float f2v = S[OW + 7*28 + v];
                    S[OB + (0*5+i)*28 + v] = dvv * f0;
                    S[OB + (1*5+i)*28 + v] = dvv * f1;
                    S[OB + (2*5+i)*28 + v] = dvv * f2v;
                }
            }
            WSYNC();

            // ---- P2: FP[3i+c][e] = g[i][e]*sum_u h[u,e]*B[c][i][u] ----
            for (int r = 0; r < 2; ++r) {
                int idx = r*64 + lane;
                if (idx < 125) {
                    int i = idx / 25, e = idx % 25;
                    unsigned m = CM[idx];
                    const float* bp = S + OB + i*28;
                    float a0 = 0.f, a1 = 0.f, a2 = 0.f;
                    while (m) {
                        int u = __builtin_ctz(m); m &= m - 1;
                        a0 += bp[u]; a1 += bp[140 + u]; a2 += bp[280 + u];
                    }
                    float gg = S[OG + i*28 + e];
                    S[OFP + (i*3+0)*28 + e] = a0 * gg;
                    S[OFP + (i*3+1)*28 + e] = a1 * gg;
                    S[OFP + (i*3+2)*28 + e] = a2 * gg;
                }
            }
            WSYNC();

            // ---- P3: ST[tp*25+v][3i+c] = dv * sum_e h[v,e]*FP[3i+c][e] ----
            for (int r = 0; r < 2; ++r) {
                int idx = r*64 + lane;
                if (idx < 125) {
                    int i = idx / 25, v = idx % 25;
                    unsigned m = RM[idx];
                    const float* fp = S + OFP + i*3*28;
                    float a0 = 0.f, a1 = 0.f, a2 = 0.f;
                    while (m) {
                        int e = __builtin_ctz(m); m &= m - 1;
                        a0 += fp[e]; a1 += fp[28 + e]; a2 += fp[56 + e];
                    }
                    float dd = S[ODV + i*28 + v];
                    float* st = S + OST + (tp*25 + v)*20 + i*3;
                    st[0] = a0 * dd; st[1] = a1 * dd; st[2] = a2 * dd;
                }
            }
            WSYNC();
        }

        // ---- P4: MLP + relu, o-paired for v_pk_fma_f32, nt stores ----
        if (lane < 50) {
            const float* st = S + OST + lane*20;
            f4 s0 = *(const f4*)(st+0), s1 = *(const f4*)(st+4),
               s2 = *(const f4*)(st+8), s3 = *(const f4*)(st+12);
            s3.w = 0.f;
            float* ob = out + (size_t)b*CO*7500 + (size_t)pp*50 + lane;
            #pragma unroll 2
            for (int o2 = 0; o2 < 32; ++o2) {
                int o = 2*o2;
                const float* wa = wmlp + o*15;   // uniform -> scalar loads
                const float* wb = wa + 15;
                f2 a = (f2){bmlp[o], bmlp[o+1]};
                a += (f2){wa[ 0], wb[ 0]} * s0.x;
                a += (f2){wa[ 1], wb[ 1]} * s0.y;
                a += (f2){wa[ 2], wb[ 2]} * s0.z;
                a += (f2){wa[ 3], wb[ 3]} * s0.w;
                a += (f2){wa[ 4], wb[ 4]} * s1.x;
                a += (f2){wa[ 5], wb[ 5]} * s1.y;
                a += (f2){wa[ 6], wb[ 6]} * s1.z;
                a += (f2){wa[ 7], wb[ 7]} * s1.w;
                a += (f2){wa[ 8], wb[ 8]} * s2.x;
                a += (f2){wa[ 9], wb[ 9]} * s2.y;
                a += (f2){wa[10], wb[10]} * s2.z;
                a += (f2){wa[11], wb[11]} * s2.w;
                a += (f2){wa[12], wb[12]} * s3.x;
                a += (f2){wa[13], wb[13]} * s3.y;
                a += (f2){wa[14], wb[14]} * s3.z;
                __builtin_nontemporal_store(fmaxf(a.x, 0.f), ob + (size_t)o*7500);
                __builtin_nontemporal_store(fmaxf(a.y, 0.f), ob + (size_t)(o+1)*7500);
            }
        }
        WSYNC();   // ST reads drained before next pair's P3 rewrites
    }
}

extern "C" void kernel_launch(void* const* d_in, const int* in_sizes, int n_in,
                              void* d_out, int out_size, void* d_ws, size_t ws_size,
                              hipStream_t stream) {
    const float* x    = (const float*)d_in[0];
    const float* h0   = (const float*)d_in[1];
    const float* h1   = (const float*)d_in[2];
    const float* h2   = (const float*)d_in[3];
    const float* h3   = (const float*)d_in[4];
    const float* h4   = (const float*)d_in[5];
    const float* wmlp = (const float*)d_in[6];
    const float* bmlp = (const float*)d_in[7];
    float* out = (float*)d_out;

    hyper_main<<<dim3(GX, 64, 1), dim3(256,1,1), 0, stream>>>(
        x, h0, h1, h2, h3, h4, wmlp, bmlp, out);
}

// Round 10
// 76.162 us; speedup vs baseline: 3.3750x; 1.1045x over previous
//
#include <hip/hip_runtime.h>

#define NE  5
#define V   25
#define NT  300
#define NC  12
#define CO  64
#define WPB 4
#define GX  38          // 38*4 = 152 wave-tasks; 150 t-pairs (2 idle)

typedef float f4 __attribute__((ext_vector_type(4)));
typedef float f2 __attribute__((ext_vector_type(2)));

// intra-wave LDS ordering: drain this wave's LDS ops + pin compiler ordering.
#define WSYNC() do { asm volatile("s_waitcnt lgkmcnt(0)" ::: "memory"); \
                     __builtin_amdgcn_sched_barrier(0); } while (0)

// select w if bit e of m set, else +0.0 (sum-equivalent to h*w, h in {0,1})
__device__ __forceinline__ float hsel(unsigned m, int e, float w) {
    int s = ((int)(m << (31 - e))) >> 31;
    return __int_as_float(__float_as_int(w) & s);
}

// per-wave scratch float offsets (rows 28 floats = 112B; OST rows 20 floats)
#define OW   0      // W[8][28]   rows 0-4 edge w, rows 5-7 feat
#define ODV  224    // DV[5][28]
#define OG   364    // G[5][28]
#define OB   504    // B[3][5][28]   (c,i,u)
#define OFP  924    // FP[15][28]    (k=3i+c, e)
#define OST  1344   // ST[50][20]    row = tp*25+v
#define SCRF 2344   // floats per wave

__global__ __launch_bounds__(256, 4) void hyper_main(
    const float* __restrict__ x,
    const float* __restrict__ h0, const float* __restrict__ h1,
    const float* __restrict__ h2, const float* __restrict__ h3,
    const float* __restrict__ h4,
    const float* __restrict__ wmlp, const float* __restrict__ bmlp,
    float* __restrict__ out)
{
    __shared__ unsigned RM[125];   // row masks [i*25+v] over e
    __shared__ unsigned CM[125];   // col masks [i*25+e] over u
    __shared__ float    DE[125];   // 1/degree_e
    __shared__ __align__(16) float SCR[WPB][SCRF];

    const int tid  = threadIdx.x;
    const int lane = tid & 63;
    const int wid  = tid >> 6;
    const int b    = blockIdx.y;

    // ---- block init (all branches within 256 threads) ----
    if (tid < 125) {
        int i = tid / 25, v = tid % 25;
        const float* hp = (i==0)?h0:(i==1)?h1:(i==2)?h2:(i==3)?h3:h4;
        unsigned m = 0;
        for (int e = 0; e < V; ++e) if (hp[v*V + e] != 0.f) m |= (1u << e);
        RM[tid] = m;
    } else if (tid < 250) {
        int idx = tid - 125, i = idx / 25, e = idx % 25;
        const float* hp = (i==0)?h0:(i==1)?h1:(i==2)?h2:(i==3)?h3:h4;
        unsigned m = 0; float s = 0.f;
        for (int u = 0; u < V; ++u) {
            float hv = hp[u*V + e];
            s += hv;
            if (hv != 0.f) m |= (1u << u);
        }
        CM[idx] = m;
        DE[idx] = (s != 0.f) ? __fdiv_rn(1.f, s) : 0.f;
    }
    __syncthreads();   // only block-wide barrier

    const int pp = blockIdx.x * WPB + wid;   // ONE t-pair per wave
    if (pp >= NT/2) return;

    float* S = SCR[wid];

    // ---- prefetch lane constants: item q = r*64+lane over 200 = 8ch x 25e ----
    const float* xb[4]; int lo[4];
    {
        #pragma unroll
        for (int r = 0; r < 4; ++r) {
            int q  = r*64 + lane;
            int qq = (q < 200) ? q : 0;
            int ch = qq / 25, e = qq % 25;
            int xc = (ch < 5) ? (ch + 6 + (ch >= 2 ? 1 : 0)) : (ch - 5);
            lo[r] = OW + ch*28 + e;
            xb[r] = x + (size_t)(b*NC + xc)*NT*V + e;
        }
    }
    const bool act3 = (lane < 8);      // r=3 valid items: q=192..199

    // prologue prefetch: t = 2*pp
    float pf0, pf1, pf2, pf3;
    {
        int t0 = 2 * pp;
        pf0 = xb[0][t0*V]; pf1 = xb[1][t0*V];
        pf2 = xb[2][t0*V]; pf3 = xb[3][t0*V];
    }

    for (int tp = 0; tp < 2; ++tp) {

        // ---- commit prefetched W (prev t's W-reads drained by prior WSYNC) ----
        S[lo[0]] = pf0; S[lo[1]] = pf1; S[lo[2]] = pf2;
        if (act3) S[lo[3]] = pf3;
        WSYNC();

        // ---- issue next-t prefetch (hidden under P1-P3 compute) ----
        if (tp == 0) {
            int tn = 2*pp + 1;
            pf0 = xb[0][tn*V]; pf1 = xb[1][tn*V];
            pf2 = xb[2][tn*V]; pf3 = xb[3][tn*V];
        }

        // ---- P1: dv (bit-exact numpy fp32 association) + g + B fused ----
        for (int r = 0; r < 2; ++r) {
            int idx = r*64 + lane;
            if (idx < 125) {
                int i = idx / 25, v = idx % 25;
                unsigned m = RM[idx];
                const float* wi = S + OW + i*28;
                f4 w0 = *(const f4*)(wi+0),  w1 = *(const f4*)(wi+4),
                   w2 = *(const f4*)(wi+8),  w3 = *(const f4*)(wi+12),
                   w4 = *(const f4*)(wi+16), w5 = *(const f4*)(wi+20),
                   w6 = *(const f4*)(wi+24);
                float L0 = 0.f, L1 = 0.f, L2 = 0.f, L3 = 0.f;
                L0=__fadd_rn(L0,hsel(m, 0,w0.x)); L1=__fadd_rn(L1,hsel(m, 1,w0.y));
                L2=__fadd_rn(L2,hsel(m, 2,w0.z)); L3=__fadd_rn(L3,hsel(m, 3,w0.w));
                L0=__fadd_rn(L0,hsel(m, 4,w1.x)); L1=__fadd_rn(L1,hsel(m, 5,w1.y));
                L2=__fadd_rn(L2,hsel(m, 6,w1.z)); L3=__fadd_rn(L3,hsel(m, 7,w1.w));
                L0=__fadd_rn(L0,hsel(m, 8,w2.x)); L1=__fadd_rn(L1,hsel(m, 9,w2.y));
                L2=__fadd_rn(L2,hsel(m,10,w2.z)); L3=__fadd_rn(L3,hsel(m,11,w2.w));
                L0=__fadd_rn(L0,hsel(m,12,w3.x)); L1=__fadd_rn(L1,hsel(m,13,w3.y));
                L2=__fadd_rn(L2,hsel(m,14,w3.z)); L3=__fadd_rn(L3,hsel(m,15,w3.w));
                L0=__fadd_rn(L0,hsel(m,16,w4.x)); L1=__fadd_rn(L1,hsel(m,17,w4.y));
                L2=__fadd_rn(L2,hsel(m,18,w4.z)); L3=__fadd_rn(L3,hsel(m,19,w4.w));
                L0=__fadd_rn(L0,hsel(m,20,w5.x)); L1=__fadd_rn(L1,hsel(m,21,w5.y));
                L2=__fadd_rn(L2,hsel(m,22,w5.z)); L3=__fadd_rn(L3,hsel(m,23,w5.w));
                float s = __fadd_rn(__fadd_rn(L0,L1), __fadd_rn(L2,L3));
                s = __fadd_rn(s, hsel(m, 24, w6.x));
                float dvv = (s > 0.f) ? (float)(1.0 / sqrt((double)s)) : 0.f;
                S[ODV + i*28 + v] = dvv;
                S[OG  + i*28 + v] = S[OW + i*28 + v] * DE[idx];
                float f0 = S[OW + 5*28 + v];
                float f1 = S[OW + 6*28 + v];
                float f2v = S[OW + 7*28 + v];
                S[OB + (0*5+i)*28 + v] = dvv * f0;
                S[OB + (1*5+i)*28 + v] = dvv * f1;
                S[OB + (2*5+i)*28 + v] = dvv * f2v;
            }
        }
        WSYNC();

        // ---- P2: FP[3i+c][e] = g[i][e]*sum_u h[u,e]*B[c][i][u] ----
        for (int r = 0; r < 2; ++r) {
            int idx = r*64 + lane;
            if (idx < 125) {
                int i = idx / 25, e = idx % 25;
                unsigned m = CM[idx];
                const float* bp = S + OB + i*28;
                float a0 = 0.f, a1 = 0.f, a2 = 0.f;
                while (m) {
                    int u = __builtin_ctz(m); m &= m - 1;
                    a0 += bp[u]; a1 += bp[140 + u]; a2 += bp[280 + u];
                }
                float gg = S[OG + i*28 + e];
                S[OFP + (i*3+0)*28 + e] = a0 * gg;
                S[OFP + (i*3+1)*28 + e] = a1 * gg;
                S[OFP + (i*3+2)*28 + e] = a2 * gg;
            }
        }
        WSYNC();

        // ---- P3: ST[tp*25+v][3i+c] = dv * sum_e h[v,e]*FP[3i+c][e] ----
        for (int r = 0; r < 2; ++r) {
            int idx = r*64 + lane;
            if (idx < 125) {
                int i = idx / 25, v = idx % 25;
                unsigned m = RM[idx];
                const float* fp = S + OFP + i*3*28;
                float a0 = 0.f, a1 = 0.f, a2 = 0.f;
                while (m) {
                    int e = __builtin_ctz(m); m &= m - 1;
                    a0 += fp[e]; a1 += fp[28 + e]; a2 += fp[56 + e];
                }
                float dd = S[ODV + i*28 + v];
                float* st = S + OST + (tp*25 + v)*20 + i*3;
                st[0] = a0 * dd; st[1] = a1 * dd; st[2] = a2 * dd;
            }
        }
        WSYNC();
    }

    // ---- P4: MLP + relu, o-paired for v_pk_fma_f32, nt stores ----
    if (lane < 50) {
        const float* st = S + OST + lane*20;
        f4 s0 = *(const f4*)(st+0), s1 = *(const f4*)(st+4),
           s2 = *(const f4*)(st+8), s3 = *(const f4*)(st+12);
        s3.w = 0.f;
        float* ob = out + (size_t)b*CO*7500 + (size_t)pp*50 + lane;
        #pragma unroll 2
        for (int o2 = 0; o2 < 32; ++o2) {
            int o = 2*o2;
            const float* wa = wmlp + o*15;   // uniform -> scalar loads
            const float* wb = wa + 15;
            f2 a = (f2){bmlp[o], bmlp[o+1]};
            a += (f2){wa[ 0], wb[ 0]} * s0.x;
            a += (f2){wa[ 1], wb[ 1]} * s0.y;
            a += (f2){wa[ 2], wb[ 2]} * s0.z;
            a += (f2){wa[ 3], wb[ 3]} * s0.w;
            a += (f2){wa[ 4], wb[ 4]} * s1.x;
            a += (f2){wa[ 5], wb[ 5]} * s1.y;
            a += (f2){wa[ 6], wb[ 6]} * s1.z;
            a += (f2){wa[ 7], wb[ 7]} * s1.w;
            a += (f2){wa[ 8], wb[ 8]} * s2.x;
            a += (f2){wa[ 9], wb[ 9]} * s2.y;
            a += (f2){wa[10], wb[10]} * s2.z;
            a += (f2){wa[11], wb[11]} * s2.w;
            a += (f2){wa[12], wb[12]} * s3.x;
            a += (f2){wa[13], wb[13]} * s3.y;
            a += (f2){wa[14], wb[14]} * s3.z;
            __builtin_nontemporal_store(fmaxf(a.x, 0.f), ob + (size_t)o*7500);
            __builtin_nontemporal_store(fmaxf(a.y, 0.f), ob + (size_t)(o+1)*7500);
        }
    }
}

extern "C" void kernel_launch(void* const* d_in, const int* in_sizes, int n_in,
                              void* d_out, int out_size, void* d_ws, size_t ws_size,
                              hipStream_t stream) {
    const float* x    = (const float*)d_in[0];
    const float* h0   = (const float*)d_in[1];
    const float* h1   = (const float*)d_in[2];
    const float* h2   = (const float*)d_in[3];
    const float* h3   = (const float*)d_in[4];
    const float* h4   = (const float*)d_in[5];
    const float* wmlp = (const float*)d_in[6];
    const float* bmlp = (const float*)d_in[7];
    float* out = (float*)d_out;

    hyper_main<<<dim3(GX, 64, 1), dim3(256,1,1), 0, stream>>>(
        x, h0, h1, h2, h3, h4, wmlp, bmlp, out);
}

// Round 11
// 76.112 us; speedup vs baseline: 3.3772x; 1.0007x over previous
//
#include <hip/hip_runtime.h>

#define NE  5
#define V   25
#define NT  300
#define NC  12
#define CO  64
#define WPB 4
#define GX  38          // 38*4 = 152 wave-tasks; 150 t-pairs (2 idle)

typedef float f4 __attribute__((ext_vector_type(4)));
typedef float f2 __attribute__((ext_vector_type(2)));

// intra-wave LDS ordering: drain this wave's LDS ops + pin compiler ordering.
#define WSYNC() do { asm volatile("s_waitcnt lgkmcnt(0)" ::: "memory"); \
                     __builtin_amdgcn_sched_barrier(0); } while (0)

// select w if bit e of m set, else +0.0 (sum-equivalent to h*w, h in {0,1})
__device__ __forceinline__ float hsel(unsigned m, int e, float w) {
    int s = ((int)(m << (31 - e))) >> 31;
    return __int_as_float(__float_as_int(w) & s);
}

// per-wave scratch float offsets (both t's of the pair live simultaneously)
#define ODV  0      // DV[2][5][28]        = 280
#define OFP  280    // FP[2][15][28]       = 840   (k=3i+c, e)
#define OWB  1120   // W [2][8][28]        = 448   rows 0-4 edge w, 5-7 feat
#define OBB  1568   // B [2][3][5][28]     = 840   (c,i,u)
#define OST  1408   // ST[50][20] = 1000, overlays dead OW tail + OB (after P2)
#define SCRF 2408   // floats per wave (9632B)

__global__ __launch_bounds__(256, 4) void hyper_main(
    const float* __restrict__ x,
    const float* __restrict__ h0, const float* __restrict__ h1,
    const float* __restrict__ h2, const float* __restrict__ h3,
    const float* __restrict__ h4,
    const float* __restrict__ wmlp, const float* __restrict__ bmlp,
    float* __restrict__ out)
{
    __shared__ unsigned RM[125];   // row masks [i*25+v] over e
    __shared__ unsigned CM[125];   // col masks [i*25+e] over u
    __shared__ float    DE[125];   // 1/degree_e
    __shared__ __align__(16) float SCR[WPB][SCRF];

    const int tid  = threadIdx.x;
    const int lane = tid & 63;
    const int wid  = tid >> 6;
    const int b    = blockIdx.y;

    // ---- block init (all branches within 256 threads) ----
    if (tid < 125) {
        int i = tid / 25, v = tid % 25;
        const float* hp = (i==0)?h0:(i==1)?h1:(i==2)?h2:(i==3)?h3:h4;
        unsigned m = 0;
        for (int e = 0; e < V; ++e) if (hp[v*V + e] != 0.f) m |= (1u << e);
        RM[tid] = m;
    } else if (tid < 250) {
        int idx = tid - 125, i = idx / 25, e = idx % 25;
        const float* hp = (i==0)?h0:(i==1)?h1:(i==2)?h2:(i==3)?h3:h4;
        unsigned m = 0; float s = 0.f;
        for (int u = 0; u < V; ++u) {
            float hv = hp[u*V + e];
            s += hv;
            if (hv != 0.f) m |= (1u << u);
        }
        CM[idx] = m;
        DE[idx] = (s != 0.f) ? __fdiv_rn(1.f, s) : 0.f;
    }
    __syncthreads();   // only block-wide barrier

    const int pp = blockIdx.x * WPB + wid;   // one t-pair per wave
    if (pp >= NT/2) return;

    float* S = SCR[wid];

    // ---- prologue: load BOTH t's 8 channels x 25 (400 items, 7 rounds) ----
    float pf[7]; int lo[7];
    #pragma unroll
    for (int r = 0; r < 7; ++r) {
        int q  = r*64 + lane;
        int qq = (q < 400) ? q : 0;
        int tt = qq / 200, rr = qq % 200, ch = rr / 25, e = rr % 25;
        int xc = (ch < 5) ? (ch + 6 + (ch >= 2 ? 1 : 0)) : (ch - 5);
        lo[r] = OWB + tt*224 + ch*28 + e;
        pf[r] = x[((size_t)(b*NC + xc)*NT + (2*pp + tt))*V + e];
    }
    #pragma unroll
    for (int r = 0; r < 6; ++r) S[lo[r]] = pf[r];
    if (lane < 16) S[lo[6]] = pf[6];
    WSYNC();

    // ---- P1: dv (bit-exact numpy fp32 association) + B, both t's ----
    #pragma unroll
    for (int r = 0; r < 4; ++r) {
        int idx = r*64 + lane;
        if (idx < 250) {
            int tt  = (idx >= 125) ? 1 : 0;
            int rem = idx - (tt ? 125 : 0);
            int i = rem / 25, v = rem % 25;
            unsigned m = RM[rem];
            const float* wi = S + OWB + tt*224 + i*28;
            f4 w0 = *(const f4*)(wi+0),  w1 = *(const f4*)(wi+4),
               w2 = *(const f4*)(wi+8),  w3 = *(const f4*)(wi+12),
               w4 = *(const f4*)(wi+16), w5 = *(const f4*)(wi+20),
               w6 = *(const f4*)(wi+24);
            float L0 = 0.f, L1 = 0.f, L2 = 0.f, L3 = 0.f;
            L0=__fadd_rn(L0,hsel(m, 0,w0.x)); L1=__fadd_rn(L1,hsel(m, 1,w0.y));
            L2=__fadd_rn(L2,hsel(m, 2,w0.z)); L3=__fadd_rn(L3,hsel(m, 3,w0.w));
            L0=__fadd_rn(L0,hsel(m, 4,w1.x)); L1=__fadd_rn(L1,hsel(m, 5,w1.y));
            L2=__fadd_rn(L2,hsel(m, 6,w1.z)); L3=__fadd_rn(L3,hsel(m, 7,w1.w));
            L0=__fadd_rn(L0,hsel(m, 8,w2.x)); L1=__fadd_rn(L1,hsel(m, 9,w2.y));
            L2=__fadd_rn(L2,hsel(m,10,w2.z)); L3=__fadd_rn(L3,hsel(m,11,w2.w));
            L0=__fadd_rn(L0,hsel(m,12,w3.x)); L1=__fadd_rn(L1,hsel(m,13,w3.y));
            L2=__fadd_rn(L2,hsel(m,14,w3.z)); L3=__fadd_rn(L3,hsel(m,15,w3.w));
            L0=__fadd_rn(L0,hsel(m,16,w4.x)); L1=__fadd_rn(L1,hsel(m,17,w4.y));
            L2=__fadd_rn(L2,hsel(m,18,w4.z)); L3=__fadd_rn(L3,hsel(m,19,w4.w));
            L0=__fadd_rn(L0,hsel(m,20,w5.x)); L1=__fadd_rn(L1,hsel(m,21,w5.y));
            L2=__fadd_rn(L2,hsel(m,22,w5.z)); L3=__fadd_rn(L3,hsel(m,23,w5.w));
            float s = __fadd_rn(__fadd_rn(L0,L1), __fadd_rn(L2,L3));
            s = __fadd_rn(s, hsel(m, 24, w6.x));
            float dvv = (s > 0.f) ? (float)(1.0 / sqrt((double)s)) : 0.f;
            S[ODV + tt*140 + i*28 + v] = dvv;
            float f0  = S[OWB + tt*224 + 5*28 + v];
            float f1  = S[OWB + tt*224 + 6*28 + v];
            float f2v = S[OWB + tt*224 + 7*28 + v];
            S[OBB + tt*420 + (0*5+i)*28 + v] = dvv * f0;
            S[OBB + tt*420 + (1*5+i)*28 + v] = dvv * f1;
            S[OBB + tt*420 + (2*5+i)*28 + v] = dvv * f2v;
        }
    }
    WSYNC();

    // ---- P2: FP[tt][3i+c][e] = (w[e]*de[e]) * sum_u h[u,e]*B[tt][c][i][u] ----
    #pragma unroll
    for (int r = 0; r < 4; ++r) {
        int idx = r*64 + lane;
        if (idx < 250) {
            int tt  = (idx >= 125) ? 1 : 0;
            int rem = idx - (tt ? 125 : 0);
            int i = rem / 25, e = rem % 25;
            unsigned m = CM[rem];
            const float* bp = S + OBB + tt*420 + i*28;
            float a0 = 0.f, a1 = 0.f, a2 = 0.f;
            while (m) {
                int u = __builtin_ctz(m); m &= m - 1;
                a0 += bp[u]; a1 += bp[140 + u]; a2 += bp[280 + u];
            }
            float gg = S[OWB + tt*224 + i*28 + e] * DE[rem];  // same ops as before
            S[OFP + tt*420 + (i*3+0)*28 + e] = a0 * gg;
            S[OFP + tt*420 + (i*3+1)*28 + e] = a1 * gg;
            S[OFP + tt*420 + (i*3+2)*28 + e] = a2 * gg;
        }
    }
    WSYNC();

    // ---- P3: ST[tt*25+v][3i+c] = dv * sum_e h[v,e]*FP[tt][3i+c][e] ----
    // (OST overlays OW/OB, both dead after P2)
    #pragma unroll
    for (int r = 0; r < 4; ++r) {
        int idx = r*64 + lane;
        if (idx < 250) {
            int tt  = (idx >= 125) ? 1 : 0;
            int rem = idx - (tt ? 125 : 0);
            int i = rem / 25, v = rem % 25;
            unsigned m = RM[rem];
            const float* fp = S + OFP + tt*420 + i*3*28;
            float a0 = 0.f, a1 = 0.f, a2 = 0.f;
            while (m) {
                int e = __builtin_ctz(m); m &= m - 1;
                a0 += fp[e]; a1 += fp[28 + e]; a2 += fp[56 + e];
            }
            float dd = S[ODV + tt*140 + i*28 + v];
            float* st = S + OST + (tt*25 + v)*20 + i*3;
            st[0] = a0 * dd; st[1] = a1 * dd; st[2] = a2 * dd;
        }
    }
    WSYNC();

    // ---- P4: MLP + relu, o-paired for v_pk_fma_f32, nt stores ----
    if (lane < 50) {
        const float* st = S + OST + lane*20;
        f4 s0 = *(const f4*)(st+0), s1 = *(const f4*)(st+4),
           s2 = *(const f4*)(st+8), s3 = *(const f4*)(st+12);
        s3.w = 0.f;
        float* ob = out + (size_t)b*CO*7500 + (size_t)pp*50 + lane;
        #pragma unroll 2
        for (int o2 = 0; o2 < 32; ++o2) {
            int o = 2*o2;
            const float* wa = wmlp + o*15;   // uniform -> scalar loads
            const float* wb = wa + 15;
            f2 a = (f2){bmlp[o], bmlp[o+1]};
            a += (f2){wa[ 0], wb[ 0]} * s0.x;
            a += (f2){wa[ 1], wb[ 1]} * s0.y;
            a += (f2){wa[ 2], wb[ 2]} * s0.z;
            a += (f2){wa[ 3], wb[ 3]} * s0.w;
            a += (f2){wa[ 4], wb[ 4]} * s1.x;
            a += (f2){wa[ 5], wb[ 5]} * s1.y;
            a += (f2){wa[ 6], wb[ 6]} * s1.z;
            a += (f2){wa[ 7], wb[ 7]} * s1.w;
            a += (f2){wa[ 8], wb[ 8]} * s2.x;
            a += (f2){wa[ 9], wb[ 9]} * s2.y;
            a += (f2){wa[10], wb[10]} * s2.z;
            a += (f2){wa[11], wb[11]} * s2.w;
            a += (f2){wa[12], wb[12]} * s3.x;
            a += (f2){wa[13], wb[13]} * s3.y;
            a += (f2){wa[14], wb[14]} * s3.z;
            __builtin_nontemporal_store(fmaxf(a.x, 0.f), ob + (size_t)o*7500);
            __builtin_nontemporal_store(fmaxf(a.y, 0.f), ob + (size_t)(o+1)*7500);
        }
    }
}

extern "C" void kernel_launch(void* const* d_in, const int* in_sizes, int n_in,
                              void* d_out, int out_size, void* d_ws, size_t ws_size,
                              hipStream_t stream) {
    const float* x    = (const float*)d_in[0];
    const float* h0   = (const float*)d_in[1];
    const float* h1   = (const float*)d_in[2];
    const float* h2   = (const float*)d_in[3];
    const float* h3   = (const float*)d_in[4];
    const float* h4   = (const float*)d_in[5];
    const float* wmlp = (const float*)d_in[6];
    const float* bmlp = (const float*)d_in[7];
    float* out = (float*)d_out;

    hyper_main<<<dim3(GX, 64, 1), dim3(256,1,1), 0, stream>>>(
        x, h0, h1, h2, h3, h4, wmlp, bmlp, out);
}